// Round 4
// baseline (177.556 us; speedup 1.0000x reference)
//
#include <hip/hip_runtime.h>
#include <stdint.h>

typedef unsigned short u16;
typedef unsigned int u32;

#define NTOT 8192          // 2B rows
#define BH   4096          // B
#define DD   128           // feature dim
#define COLSPLIT 16
#define COLS_PER_SPLIT (NTOT / COLSPLIT)   // 512
#define TILE_COLS 64
#define TILES_PER_SPLIT (COLS_PER_SPLIT / TILE_COLS) // 8
#define ROWS_PER_BLOCK 128
#define ROWS_PER_WAVE 32
#define TILE_U16 (TILE_COLS * DD)          // 8192 u16 = 16 KB per buffer
#define NROWBLK (NTOT / ROWS_PER_BLOCK)    // 64
#define NEG_INF (-3.0e38f)
#define SCALE_IN 2.68579144f   // sqrt(log2(e)/0.2): MFMA output is sim*log2(e) -> exp2 domain
#define LN2F 0.6931471805599453f

typedef __bf16 bf16x8 __attribute__((ext_vector_type(8)));
typedef float  f32x4  __attribute__((ext_vector_type(4)));

__device__ __forceinline__ u16 f2bf(float f) {
  u32 u = __float_as_uint(f);
  return (u16)((u + 0x7fffu + ((u >> 16) & 1u)) >> 16);  // RNE
}

// single-instruction v_exp_f32 (avoid OCML multi-instruction exp2f)
__device__ __forceinline__ float fexp2(float x) {
#if __has_builtin(__builtin_amdgcn_exp2f)
  return __builtin_amdgcn_exp2f(x);
#else
  float r; asm("v_exp_f32 %0, %1" : "=v"(r) : "v"(x)); return r;
#endif
}

// ---- kernel 1: fp32 z1,z2 -> scaled bf16 zb[8192][128]; zero out + cnt ---
__global__ __launch_bounds__(256) void ntx_convert(
    const float* __restrict__ z1, const float* __restrict__ z2,
    u16* __restrict__ zb, float* __restrict__ out, u32* __restrict__ cnt) {
  if (blockIdx.x == 0) {
    if (threadIdx.x == 0) out[0] = 0.f;                 // replaces memset node
    if (threadIdx.x < NROWBLK) cnt[threadIdx.x] = 0u;   // workspace is poisoned each iter
  }
  const int i = (blockIdx.x * 256 + threadIdx.x) * 4;   // 1024 blocks cover 1,048,576 floats
  const int half = BH * DD;
  float4 v = (i < half) ? *reinterpret_cast<const float4*>(z1 + i)
                        : *reinterpret_cast<const float4*>(z2 + (i - half));
  u32 lo = (u32)f2bf(v.x * SCALE_IN) | ((u32)f2bf(v.y * SCALE_IN) << 16);
  u32 hi = (u32)f2bf(v.z * SCALE_IN) | ((u32)f2bf(v.w * SCALE_IN) << 16);
  uint2 o; o.x = lo; o.y = hi;
  *reinterpret_cast<uint2*>(zb + i) = o;
}

// ---- kernel 2: flash-style row logsumexp over a col-split + fused finish --
// grid = (64 rowblocks, 16 colsplits) = 1024 blocks, block = 256 (4 waves x 32 rows)
// vs round 3: (a) ntx_finish fused in via last-block-per-rowblock atomic merge
// (saves one kernel + one graph-node gap of fixed overhead); (b) T5 setprio(1)
// around the ds_read+MFMA cluster (attn-shaped kernel: waves drift between
// MFMA phase and VALU/TRANS softmax phase within a tile -> m191 regime).
// Staging: global_load_lds width-16, double-buffered LDS, XOR-swizzle applied
// both-sides (pre-swizzled global source + same XOR on ds_read, rule #21).
__global__ __launch_bounds__(256, 4) void ntx_main(
    const u16* __restrict__ zb,
    float* __restrict__ m_part, float* __restrict__ l_part,
    float* __restrict__ st_part, u32* __restrict__ cnt,
    float* __restrict__ out) {
  __shared__ u16 lds_tile[2][TILE_U16];  // 2 x 16 KB

  const int tid  = threadIdx.x;
  const int wave = tid >> 6;
  const int lane = tid & 63;
  const int l15  = lane & 15;
  const int q    = lane >> 4;

  const int rwave = blockIdx.x * ROWS_PER_BLOCK + wave * ROWS_PER_WAVE;
  const int split = blockIdx.y;
  const int col0  = split * COLS_PER_SPLIT;

  // ---- staging: 16 KB tile = 16 x 1KB global_load_lds_dwordx4 (4 per wave).
  // Instruction j4 writes LDS linear [j4*1024 + lane*16). That LDS slot is
  // (col = j4*4 + (lane>>4), slot = lane&15); we want it to hold global
  // 16B-chunk (slot ^ (col&7)) of column ct0+col -> pre-swizzle the source.
#define STAGE_TILE(buf, ct0_)                                                  \
  {                                                                            \
    _Pragma("unroll")                                                          \
    for (int j = 0; j < 4; ++j) {                                              \
      const int j4   = wave * 4 + j;                                           \
      const int col  = j4 * 4 + (lane >> 4);                                   \
      const int slot = (lane & 15) ^ (col & 7);                                \
      const u16* srcp = zb + ((ct0_) + col) * DD + slot * 8;                   \
      u16* dstp = &lds_tile[(buf)][j4 * 512 + lane * 8];                       \
      __builtin_amdgcn_global_load_lds(                                        \
          (const __attribute__((address_space(1))) u32*)srcp,                  \
          (__attribute__((address_space(3))) u32*)dstp, 16, 0, 0);             \
    }                                                                          \
  }

  // A-fragments: 16x16x32 bf16 A layout: row = lane&15, k = (lane>>4)*8 + j
  bf16x8 afrag[2][4];
#pragma unroll
  for (int rt = 0; rt < 2; ++rt)
#pragma unroll
    for (int kk = 0; kk < 4; ++kk) {
      const int r = rwave + rt * 16 + l15;
      afrag[rt][kk] = *reinterpret_cast<const bf16x8*>(zb + r * DD + kk * 32 + q * 8);
    }

  float m_run[2][4], l_run[2][4], stv[2][4];
#pragma unroll
  for (int rt = 0; rt < 2; ++rt)
#pragma unroll
    for (int r = 0; r < 4; ++r) { m_run[rt][r] = NEG_INF; l_run[rt][r] = 0.f; stv[rt][r] = NEG_INF; }

  STAGE_TILE(0, col0)          // prologue: tile 0 into buf 0
  __syncthreads();

  for (int t = 0; t < TILES_PER_SPLIT; ++t) {
    const int ct0 = col0 + t * TILE_COLS;
    const int cur = t & 1;

    // issue next tile's loads NOW; they land during this tile's compute
    if (t + 1 < TILES_PER_SPLIT) STAGE_TILE(cur ^ 1, ct0 + TILE_COLS)

    const u16* bb = &lds_tile[cur][0];

    // ---- GEMM: 32 rows x 64 cols x K=128 per wave ----
    f32x4 acc[2][4];
#pragma unroll
    for (int rt = 0; rt < 2; ++rt)
#pragma unroll
      for (int cs = 0; cs < 4; ++cs) acc[rt][cs] = (f32x4){0.f, 0.f, 0.f, 0.f};

    __builtin_amdgcn_s_setprio(1);
#pragma unroll
    for (int cs = 0; cs < 4; ++cs) {
      const int col = cs * 16 + l15;
      const int xr  = col & 7;             // read-side XOR = write-side XOR
      bf16x8 bfrag[4];
#pragma unroll
      for (int kk = 0; kk < 4; ++kk)
        bfrag[kk] = *reinterpret_cast<const bf16x8*>(
            bb + col * DD + (((kk * 4 + q) ^ xr) * 8));
#pragma unroll
      for (int rt = 0; rt < 2; ++rt)
#pragma unroll
        for (int kk = 0; kk < 4; ++kk)
          acc[rt][cs] = __builtin_amdgcn_mfma_f32_16x16x32_bf16(
              afrag[rt][kk], bfrag[kk], acc[rt][cs], 0, 0, 0);
    }
    __builtin_amdgcn_s_setprio(0);

    // ---- diag mask + target extraction (only in the <=2 tiles that need it) ----
    const bool has_diag = (rwave >= ct0) && (rwave < ct0 + TILE_COLS);
    const int  trow     = rwave ^ BH;
    const bool has_tgt  = (trow >= ct0) && (trow < ct0 + TILE_COLS);
    if (has_diag || has_tgt) {
#pragma unroll
      for (int rt = 0; rt < 2; ++rt)
#pragma unroll
        for (int r = 0; r < 4; ++r) {
          const int grow = rwave + rt * 16 + q * 4 + r;  // C layout: row=(lane>>4)*4+reg
#pragma unroll
          for (int cs = 0; cs < 4; ++cs) {
            const int gcol = ct0 + cs * 16 + l15;        // C layout: col=lane&15
            float v = acc[rt][cs][r];
            if (gcol == (grow ^ BH)) stv[rt][r] = fmaxf(stv[rt][r], v);
            if (gcol == grow) acc[rt][cs][r] = NEG_INF;
          }
        }
    }

    // ---- per-lane online logsumexp update (NO cross-lane traffic) ----
#pragma unroll
    for (int rt = 0; rt < 2; ++rt)
#pragma unroll
      for (int r = 0; r < 4; ++r) {
        float mx = fmaxf(fmaxf(acc[rt][0][r], acc[rt][1][r]),
                         fmaxf(acc[rt][2][r], acc[rt][3][r]));
        const float mnew = fmaxf(m_run[rt][r], mx);
        float s = 0.f;
#pragma unroll
        for (int cs = 0; cs < 4; ++cs) s += fexp2(acc[rt][cs][r] - mnew);
        l_run[rt][r] = l_run[rt][r] * fexp2(m_run[rt][r] - mnew) + s;
        m_run[rt][r] = mnew;
      }

    // one barrier per tile: built-in vmcnt/lgkm drain finishes the prefetch
    // (issued a full compute-phase ago) and closes this tile's LDS reads.
    __syncthreads();
  }

  // ---- one-time cross-lane logsumexp merge over the 16-lane row slice ----
#pragma unroll
  for (int rt = 0; rt < 2; ++rt)
#pragma unroll
    for (int r = 0; r < 4; ++r) {
      float m = m_run[rt][r], l = l_run[rt][r];
#pragma unroll
      for (int off = 1; off < 16; off <<= 1) {
        const float mo = __shfl_xor(m, off, 64);
        const float lo = __shfl_xor(l, off, 64);
        const float mn = fmaxf(m, mo);
        l = l * fexp2(m - mn) + lo * fexp2(mo - mn);
        m = mn;
      }
      float sv = stv[rt][r];
#pragma unroll
      for (int off = 1; off < 16; off <<= 1) sv = fmaxf(sv, __shfl_xor(sv, off, 64));
      if (l15 == 0) {
        const int grow = rwave + rt * 16 + q * 4 + r;
        m_part[split * NTOT + grow] = m;
        l_part[split * NTOT + grow] = l;
        const int tcol = grow ^ BH;
        if (tcol >= col0 && tcol < col0 + COLS_PER_SPLIT) st_part[grow] = sv;  // one writer/row
      }
    }
#undef STAGE_TILE

  // ---- fused finish: last split-block for this rowblock merges all splits ---
  __threadfence();                       // release: partials visible device-wide
  __shared__ u32 prev_cnt;
  if (tid == 0) prev_cnt = atomicAdd(&cnt[blockIdx.x], 1u);
  __syncthreads();
  if (prev_cnt != COLSPLIT - 1) return;  // uniform across block
  __threadfence();                       // acquire: see other blocks' partials

  float loss = 0.f;
  if (tid < ROWS_PER_BLOCK) {            // waves 0,1 active; 1 row/thread
    const int row = blockIdx.x * ROWS_PER_BLOCK + tid;
    float m = NEG_INF;
#pragma unroll
    for (int s = 0; s < COLSPLIT; ++s) m = fmaxf(m, m_part[s * NTOT + row]);
    float l = 0.f;
#pragma unroll
    for (int s = 0; s < COLSPLIT; ++s)
      l += l_part[s * NTOT + row] * fexp2(m_part[s * NTOT + row] - m);
    loss = LN2F * (m + __log2f(l) - st_part[row]);  // back to natural-log domain
  }
  if (wave < 2) {
#pragma unroll
    for (int off = 32; off >= 1; off >>= 1) loss += __shfl_xor(loss, off, 64);
  }
  __shared__ float wsum[2];
  if (wave < 2 && lane == 0) wsum[wave] = loss;
  __syncthreads();
  if (tid == 0) atomicAdd(out, (wsum[0] + wsum[1]) * (1.0f / NTOT));
}

extern "C" void kernel_launch(void* const* d_in, const int* in_sizes, int n_in,
                              void* d_out, int out_size, void* d_ws, size_t ws_size,
                              hipStream_t stream) {
  const float* z1 = (const float*)d_in[0];
  const float* z2 = (const float*)d_in[1];
  float* out = (float*)d_out;

  // workspace: zb (2MB bf16) | m_part[16][8192] | l_part[16][8192] | st[8192] | cnt[64]
  char* ws = (char*)d_ws;
  u16*   zb      = (u16*)ws;
  float* m_part  = (float*)(ws + (size_t)NTOT * DD * 2);
  float* l_part  = m_part + COLSPLIT * NTOT;
  float* st_part = l_part + COLSPLIT * NTOT;
  u32*   cnt     = (u32*)(st_part + NTOT);

  ntx_convert<<<dim3((NTOT * DD) / (256 * 4)), dim3(256), 0, stream>>>(z1, z2, zb, out, cnt);
  ntx_main<<<dim3(NTOT / ROWS_PER_BLOCK, COLSPLIT), dim3(256), 0, stream>>>(
      zb, m_part, l_part, st_part, cnt, out);
}

// Round 5
// 92.305 us; speedup vs baseline: 1.9236x; 1.9236x over previous
//
#include <hip/hip_runtime.h>
#include <stdint.h>

typedef unsigned short u16;
typedef unsigned int u32;

#define NTOT 8192          // 2B rows
#define BH   4096          // B
#define DD   128           // feature dim
#define COLSPLIT 16
#define COLS_PER_SPLIT (NTOT / COLSPLIT)   // 512
#define TILE_COLS 64
#define TILES_PER_SPLIT (COLS_PER_SPLIT / TILE_COLS) // 8
#define ROWS_PER_BLOCK 256
#define ROWS_PER_WAVE 64
#define NRT 4              // 16-row sub-tiles per wave
#define TILE_U16 (TILE_COLS * DD)          // 8192 u16 = 16 KB per buffer
#define NEG_INF (-3.0e38f)
#define SCALE_IN 2.68579144f   // sqrt(log2(e)/0.2): MFMA output is sim*log2(e) -> exp2 domain
#define LN2F 0.6931471805599453f

typedef __bf16 bf16x8 __attribute__((ext_vector_type(8)));
typedef float  f32x4  __attribute__((ext_vector_type(4)));

__device__ __forceinline__ u16 f2bf(float f) {
  u32 u = __float_as_uint(f);
  return (u16)((u + 0x7fffu + ((u >> 16) & 1u)) >> 16);  // RNE
}

// single-instruction v_exp_f32 (avoid OCML multi-instruction exp2f)
__device__ __forceinline__ float fexp2(float x) {
#if __has_builtin(__builtin_amdgcn_exp2f)
  return __builtin_amdgcn_exp2f(x);
#else
  float r; asm("v_exp_f32 %0, %1" : "=v"(r) : "v"(x)); return r;
#endif
}

// ---- kernel 1: fp32 z1,z2 -> scaled bf16 zb[8192][128]; also zero d_out ---
__global__ __launch_bounds__(256) void ntx_convert(
    const float* __restrict__ z1, const float* __restrict__ z2,
    u16* __restrict__ zb, float* __restrict__ out) {
  if (blockIdx.x == 0 && threadIdx.x == 0) out[0] = 0.f;  // replaces memset node
  const int i = (blockIdx.x * 256 + threadIdx.x) * 4;   // 1024 blocks cover 1,048,576 floats
  const int half = BH * DD;
  float4 v = (i < half) ? *reinterpret_cast<const float4*>(z1 + i)
                        : *reinterpret_cast<const float4*>(z2 + (i - half));
  u32 lo = (u32)f2bf(v.x * SCALE_IN) | ((u32)f2bf(v.y * SCALE_IN) << 16);
  u32 hi = (u32)f2bf(v.z * SCALE_IN) | ((u32)f2bf(v.w * SCALE_IN) << 16);
  uint2 o; o.x = lo; o.y = hi;
  *reinterpret_cast<uint2*>(zb + i) = o;
}

// ---- kernel 2: flash-style row logsumexp over a col-split ----------------
// grid = (32 rowblocks, 16 colsplits) = 512 blocks, block = 256 (4 waves x 64 rows)
// vs round 4: (a) REVERTED fused-finish + threadfence (device-scope fence =
// per-XCD L2 writeback/invalidate -> destroyed zb L2 residency, 3.3x regression)
// and setprio (confounded). Separate ntx_finish kernel returns.
// (b) ROWS_PER_WAVE 32 -> 64: per-wave LDS read volume is unchanged (each wave
// reads the whole 16 KB tile) but covers 2x rows -> per-CU LDS traffic HALVES
// (~10.3 us -> ~5 us pipe floor) and each wave gets 2x independent MFMA/VALU
// chains (ILP). VGPR ~200 under __launch_bounds__(256,2): no spill, 2 blocks/CU.
// Staging: global_load_lds width-16, double-buffered, both-sides XOR swizzle
// (pre-swizzled global source + same XOR on ds_read, rule #21).
__global__ __launch_bounds__(256, 2) void ntx_main(
    const u16* __restrict__ zb,
    float* __restrict__ m_part, float* __restrict__ l_part,
    float* __restrict__ st_part) {
  __shared__ u16 lds_tile[2][TILE_U16];  // 2 x 16 KB

  const int tid  = threadIdx.x;
  const int wave = tid >> 6;
  const int lane = tid & 63;
  const int l15  = lane & 15;
  const int q    = lane >> 4;

  const int rwave = blockIdx.x * ROWS_PER_BLOCK + wave * ROWS_PER_WAVE;  // 64-aligned
  const int split = blockIdx.y;
  const int col0  = split * COLS_PER_SPLIT;

  // ---- staging: 16 KB tile = 16 x 1KB global_load_lds_dwordx4 (4 per wave).
  // Instruction j4 writes LDS linear [j4*1024 + lane*16). That LDS slot is
  // (col = j4*4 + (lane>>4), slot = lane&15); we want it to hold global
  // 16B-chunk (slot ^ (col&7)) of column ct0+col -> pre-swizzle the source.
#define STAGE_TILE(buf, ct0_)                                                  \
  {                                                                            \
    _Pragma("unroll")                                                          \
    for (int j = 0; j < 4; ++j) {                                              \
      const int j4   = wave * 4 + j;                                           \
      const int col  = j4 * 4 + (lane >> 4);                                   \
      const int slot = (lane & 15) ^ (col & 7);                                \
      const u16* srcp = zb + ((ct0_) + col) * DD + slot * 8;                   \
      u16* dstp = &lds_tile[(buf)][j4 * 512 + lane * 8];                       \
      __builtin_amdgcn_global_load_lds(                                        \
          (const __attribute__((address_space(1))) u32*)srcp,                  \
          (__attribute__((address_space(3))) u32*)dstp, 16, 0, 0);             \
    }                                                                          \
  }

  STAGE_TILE(0, col0)          // prologue: tile 0 into buf 0 (issue before afrag)

  // A-fragments: 16x16x32 bf16 A layout: row = lane&15, k = (lane>>4)*8 + j
  bf16x8 afrag[NRT][4];
#pragma unroll
  for (int rt = 0; rt < NRT; ++rt)
#pragma unroll
    for (int kk = 0; kk < 4; ++kk) {
      const int r = rwave + rt * 16 + l15;
      afrag[rt][kk] = *reinterpret_cast<const bf16x8*>(zb + r * DD + kk * 32 + q * 8);
    }

  float m_run[NRT][4], l_run[NRT][4], stv[NRT][4];
#pragma unroll
  for (int rt = 0; rt < NRT; ++rt)
#pragma unroll
    for (int r = 0; r < 4; ++r) { m_run[rt][r] = NEG_INF; l_run[rt][r] = 0.f; stv[rt][r] = NEG_INF; }

  __syncthreads();

  for (int t = 0; t < TILES_PER_SPLIT; ++t) {
    const int ct0 = col0 + t * TILE_COLS;
    const int cur = t & 1;

    // issue next tile's loads NOW; they land during this tile's compute
    if (t + 1 < TILES_PER_SPLIT) STAGE_TILE(cur ^ 1, ct0 + TILE_COLS)

    const u16* bb = &lds_tile[cur][0];

    // ---- GEMM: 64 rows x 64 cols x K=128 per wave ----
    f32x4 acc[NRT][4];
#pragma unroll
    for (int rt = 0; rt < NRT; ++rt)
#pragma unroll
      for (int cs = 0; cs < 4; ++cs) acc[rt][cs] = (f32x4){0.f, 0.f, 0.f, 0.f};

#pragma unroll
    for (int cs = 0; cs < 4; ++cs) {
      const int col = cs * 16 + l15;
      const int xr  = col & 7;             // read-side XOR = write-side XOR
      bf16x8 bfrag[4];
#pragma unroll
      for (int kk = 0; kk < 4; ++kk)
        bfrag[kk] = *reinterpret_cast<const bf16x8*>(
            bb + col * DD + (((kk * 4 + q) ^ xr) * 8));
#pragma unroll
      for (int rt = 0; rt < NRT; ++rt)
#pragma unroll
        for (int kk = 0; kk < 4; ++kk)
          acc[rt][cs] = __builtin_amdgcn_mfma_f32_16x16x32_bf16(
              afrag[rt][kk], bfrag[kk], acc[rt][cs], 0, 0, 0);
    }

    // ---- diag mask + target extraction ------------------------------------
    // rwave and ct0 are both 64-aligned with TILE_COLS==ROWS_PER_WAVE==64, so
    // the wave's 64 rows hit the diagonal iff ct0 == rwave, and targets iff
    // ct0 == (rwave ^ BH).
    const bool has_diag = (ct0 == rwave);
    const bool has_tgt  = (ct0 == (rwave ^ BH));
    if (has_diag || has_tgt) {
#pragma unroll
      for (int rt = 0; rt < NRT; ++rt)
#pragma unroll
        for (int r = 0; r < 4; ++r) {
          const int grow = rwave + rt * 16 + q * 4 + r;  // C layout: row=(lane>>4)*4+reg
#pragma unroll
          for (int cs = 0; cs < 4; ++cs) {
            const int gcol = ct0 + cs * 16 + l15;        // C layout: col=lane&15
            float v = acc[rt][cs][r];
            if (gcol == (grow ^ BH)) stv[rt][r] = fmaxf(stv[rt][r], v);
            if (gcol == grow) acc[rt][cs][r] = NEG_INF;
          }
        }
    }

    // ---- per-lane online logsumexp update (NO cross-lane traffic) ----
#pragma unroll
    for (int rt = 0; rt < NRT; ++rt)
#pragma unroll
      for (int r = 0; r < 4; ++r) {
        float mx = fmaxf(fmaxf(acc[rt][0][r], acc[rt][1][r]),
                         fmaxf(acc[rt][2][r], acc[rt][3][r]));
        const float mnew = fmaxf(m_run[rt][r], mx);
        float s = 0.f;
#pragma unroll
        for (int cs = 0; cs < 4; ++cs) s += fexp2(acc[rt][cs][r] - mnew);
        l_run[rt][r] = l_run[rt][r] * fexp2(m_run[rt][r] - mnew) + s;
        m_run[rt][r] = mnew;
      }

    // one barrier per tile: built-in vmcnt/lgkm drain finishes the prefetch
    // (issued a full compute-phase ago) and closes this tile's LDS reads.
    __syncthreads();
  }

  // ---- one-time cross-lane logsumexp merge over the 16-lane row slice ----
#pragma unroll
  for (int rt = 0; rt < NRT; ++rt)
#pragma unroll
    for (int r = 0; r < 4; ++r) {
      float m = m_run[rt][r], l = l_run[rt][r];
#pragma unroll
      for (int off = 1; off < 16; off <<= 1) {
        const float mo = __shfl_xor(m, off, 64);
        const float lo = __shfl_xor(l, off, 64);
        const float mn = fmaxf(m, mo);
        l = l * fexp2(m - mn) + lo * fexp2(mo - mn);
        m = mn;
      }
      float sv = stv[rt][r];
#pragma unroll
      for (int off = 1; off < 16; off <<= 1) sv = fmaxf(sv, __shfl_xor(sv, off, 64));
      if (l15 == 0) {
        const int grow = rwave + rt * 16 + q * 4 + r;
        m_part[split * NTOT + grow] = m;
        l_part[split * NTOT + grow] = l;
        const int tcol = grow ^ BH;
        if (tcol >= col0 && tcol < col0 + COLS_PER_SPLIT) st_part[grow] = sv;  // one writer/row
      }
    }
#undef STAGE_TILE
}

// ---- kernel 3: combine splits, mean, atomicAdd --------------------------
__global__ __launch_bounds__(256) void ntx_finish(
    const float* __restrict__ m_part, const float* __restrict__ l_part,
    const float* __restrict__ st_part, float* __restrict__ out) {
  const int row = blockIdx.x * 256 + threadIdx.x;   // 32 blocks
  float m = NEG_INF;
#pragma unroll
  for (int s = 0; s < COLSPLIT; ++s) m = fmaxf(m, m_part[s * NTOT + row]);
  float l = 0.f;
#pragma unroll
  for (int s = 0; s < COLSPLIT; ++s) l += l_part[s * NTOT + row] * fexp2(m_part[s * NTOT + row] - m);
  float loss = LN2F * (m + __log2f(l) - st_part[row]);  // back to natural-log domain

#pragma unroll
  for (int off = 32; off >= 1; off >>= 1) loss += __shfl_xor(loss, off, 64);
  __shared__ float wsum[4];
  if ((threadIdx.x & 63) == 0) wsum[threadIdx.x >> 6] = loss;
  __syncthreads();
  if (threadIdx.x == 0) {
    float s = wsum[0] + wsum[1] + wsum[2] + wsum[3];
    atomicAdd(out, s * (1.0f / NTOT));
  }
}

extern "C" void kernel_launch(void* const* d_in, const int* in_sizes, int n_in,
                              void* d_out, int out_size, void* d_ws, size_t ws_size,
                              hipStream_t stream) {
  const float* z1 = (const float*)d_in[0];
  const float* z2 = (const float*)d_in[1];
  float* out = (float*)d_out;

  // workspace: zb (2MB bf16) | m_part[16][8192] | l_part[16][8192] | st[8192]
  char* ws = (char*)d_ws;
  u16*   zb      = (u16*)ws;
  float* m_part  = (float*)(ws + (size_t)NTOT * DD * 2);
  float* l_part  = m_part + COLSPLIT * NTOT;
  float* st_part = l_part + COLSPLIT * NTOT;

  ntx_convert<<<dim3((NTOT * DD) / (256 * 4)), dim3(256), 0, stream>>>(z1, z2, zb, out);
  ntx_main<<<dim3(NTOT / ROWS_PER_BLOCK, COLSPLIT), dim3(256), 0, stream>>>(
      zb, m_part, l_part, st_part);
  ntx_finish<<<dim3(NTOT / 256), dim3(256), 0, stream>>>(m_part, l_part, st_part, out);
}

// Round 6
// 88.342 us; speedup vs baseline: 2.0099x; 1.0449x over previous
//
#include <hip/hip_runtime.h>
#include <stdint.h>

typedef unsigned short u16;
typedef unsigned int u32;

#define NTOT 8192          // 2B rows
#define BH   4096          // B
#define DD   128           // feature dim
#define COLSPLIT 8
#define COLS_PER_SPLIT (NTOT / COLSPLIT)   // 1024
#define TILE_COLS 64
#define TILES_PER_SPLIT (COLS_PER_SPLIT / TILE_COLS) // 16
#define ROWS_PER_BLOCK 128
#define ROWS_PER_WAVE 32
#define TILE_U16 (TILE_COLS * DD)          // 8192 u16 = 16 KB per buffer
#define NEG_INF (-3.0e38f)
#define SCALE_IN 2.68579144f   // sqrt(log2(e)/0.2): MFMA output is sim*log2(e) -> exp2 domain
#define LN2F 0.6931471805599453f

typedef __bf16 bf16x8 __attribute__((ext_vector_type(8)));
typedef float  f32x4  __attribute__((ext_vector_type(4)));

__device__ __forceinline__ u16 f2bf(float f) {
  u32 u = __float_as_uint(f);
  return (u16)((u + 0x7fffu + ((u >> 16) & 1u)) >> 16);  // RNE
}

// single-instruction v_exp_f32 (avoid OCML multi-instruction exp2f)
__device__ __forceinline__ float fexp2(float x) {
#if __has_builtin(__builtin_amdgcn_exp2f)
  return __builtin_amdgcn_exp2f(x);
#else
  float r; asm("v_exp_f32 %0, %1" : "=v"(r) : "v"(x)); return r;
#endif
}

// ---- kernel 1: fp32 z1,z2 -> scaled bf16 zb[8192][128]; also zero d_out ---
__global__ __launch_bounds__(256) void ntx_convert(
    const float* __restrict__ z1, const float* __restrict__ z2,
    u16* __restrict__ zb, float* __restrict__ out) {
  if (blockIdx.x == 0 && threadIdx.x == 0) out[0] = 0.f;  // replaces memset node
  const int i = (blockIdx.x * 256 + threadIdx.x) * 4;   // 1024 blocks cover 1,048,576 floats
  const int half = BH * DD;
  float4 v = (i < half) ? *reinterpret_cast<const float4*>(z1 + i)
                        : *reinterpret_cast<const float4*>(z2 + (i - half));
  u32 lo = (u32)f2bf(v.x * SCALE_IN) | ((u32)f2bf(v.y * SCALE_IN) << 16);
  u32 hi = (u32)f2bf(v.z * SCALE_IN) | ((u32)f2bf(v.w * SCALE_IN) << 16);
  uint2 o; o.x = lo; o.y = hi;
  *reinterpret_cast<uint2*>(zb + i) = o;
}

// ---- kernel 2: flash-style row logsumexp over a col-split ----------------
// grid = (64 rowblocks, 8 colsplits) = 512 blocks (exactly 2/CU), block = 256
// (4 waves x 32 rows), 16 tiles of 64 cols per block.
// vs round 5: round-5 counters showed the kernel running at the SERIAL SUM of
// its pipes (MfmaUtil 14 + VALUBusy 35 = ~50% busy): within a wave softmax(t)
// depends on MFMA(t), so the phases can never overlap. Fix = 2-tile
// accumulator pipeline (T15 structure as a true dependency break): at tile t,
// MFMA(t)->acc_cur is interleaved with softmax(acc_prev, t-1), which are
// independent, so the scheduler can fill MFMA issue gaps with softmax VALU.
// Named accA/accB + manual 2-unroll (rule #20: no runtime acc indexing).
// Staging: global_load_lds width-16, double-buffered, both-sides XOR swizzle
// (pre-swizzled global source + same XOR on ds_read, rule #21), one barrier
// per tile (prefetch issued a full compute phase before the drain).
__global__ __launch_bounds__(256, 2) void ntx_main(
    const u16* __restrict__ zb,
    float* __restrict__ m_part, float* __restrict__ l_part,
    float* __restrict__ st_part) {
  __shared__ u16 lds_tile[2][TILE_U16];  // 2 x 16 KB

  const int tid  = threadIdx.x;
  const int wave = tid >> 6;
  const int lane = tid & 63;
  const int l15  = lane & 15;
  const int q    = lane >> 4;

  const int rwave = blockIdx.x * ROWS_PER_BLOCK + wave * ROWS_PER_WAVE;
  const int split = blockIdx.y;
  const int col0  = split * COLS_PER_SPLIT;

  // ---- staging: 16 KB tile = 16 x 1KB global_load_lds_dwordx4 (4 per wave).
  // Instruction j4 writes LDS linear [j4*1024 + lane*16). That LDS slot is
  // (col = j4*4 + (lane>>4), slot = lane&15); we want it to hold global
  // 16B-chunk (slot ^ (col&7)) of column ct0+col -> pre-swizzle the source.
#define STAGE_TILE(buf, ct0_)                                                  \
  {                                                                            \
    _Pragma("unroll")                                                          \
    for (int j = 0; j < 4; ++j) {                                              \
      const int j4   = wave * 4 + j;                                           \
      const int col  = j4 * 4 + (lane >> 4);                                   \
      const int slot = (lane & 15) ^ (col & 7);                                \
      const u16* srcp = zb + ((ct0_) + col) * DD + slot * 8;                   \
      u16* dstp = &lds_tile[(buf)][j4 * 512 + lane * 8];                       \
      __builtin_amdgcn_global_load_lds(                                        \
          (const __attribute__((address_space(1))) u32*)srcp,                  \
          (__attribute__((address_space(3))) u32*)dstp, 16, 0, 0);             \
    }                                                                          \
  }

  // MFMA one 64-col tile from LDS buffer BUF into ACC (zero-init included)
#define MFMA_TILE(ACC, BUF)                                                    \
  {                                                                            \
    _Pragma("unroll")                                                          \
    for (int rt = 0; rt < 2; ++rt)                                             \
      _Pragma("unroll")                                                        \
      for (int cs = 0; cs < 4; ++cs) ACC[rt][cs] = (f32x4){0.f,0.f,0.f,0.f};   \
    const u16* bb = &lds_tile[(BUF)][0];                                       \
    _Pragma("unroll")                                                          \
    for (int cs = 0; cs < 4; ++cs) {                                           \
      const int col = cs * 16 + l15;                                           \
      const int xr  = col & 7;            /* read XOR = write XOR */           \
      bf16x8 bfrag[4];                                                         \
      _Pragma("unroll")                                                        \
      for (int kk = 0; kk < 4; ++kk)                                           \
        bfrag[kk] = *reinterpret_cast<const bf16x8*>(                          \
            bb + col * DD + (((kk * 4 + q) ^ xr) * 8));                        \
      _Pragma("unroll")                                                        \
      for (int rt = 0; rt < 2; ++rt)                                           \
        _Pragma("unroll")                                                      \
        for (int kk = 0; kk < 4; ++kk)                                         \
          ACC[rt][cs] = __builtin_amdgcn_mfma_f32_16x16x32_bf16(               \
              afrag[rt][kk], bfrag[kk], ACC[rt][cs], 0, 0, 0);                 \
    }                                                                          \
  }

  // mask + online-logsumexp finish for ACC, which holds tile at col base CT0.
  // Register-only: independent of the NEXT tile's MFMA -> interleavable.
#define SOFTMAX_TILE(ACC, CT0)                                                 \
  {                                                                            \
    const int ct0_ = (CT0);                                                    \
    const bool has_diag = (rwave >= ct0_) && (rwave < ct0_ + TILE_COLS);       \
    const int  trow     = rwave ^ BH;                                          \
    const bool has_tgt  = (trow >= ct0_) && (trow < ct0_ + TILE_COLS);         \
    if (has_diag || has_tgt) {                                                 \
      _Pragma("unroll")                                                        \
      for (int rt = 0; rt < 2; ++rt)                                           \
        _Pragma("unroll")                                                      \
        for (int r = 0; r < 4; ++r) {                                          \
          const int grow = rwave + rt * 16 + q * 4 + r;                        \
          _Pragma("unroll")                                                    \
          for (int cs = 0; cs < 4; ++cs) {                                     \
            const int gcol = ct0_ + cs * 16 + l15;                             \
            float v = ACC[rt][cs][r];                                          \
            if (gcol == (grow ^ BH)) stv[rt][r] = fmaxf(stv[rt][r], v);        \
            if (gcol == grow) ACC[rt][cs][r] = NEG_INF;                        \
          }                                                                    \
        }                                                                      \
    }                                                                          \
    _Pragma("unroll")                                                          \
    for (int rt = 0; rt < 2; ++rt)                                             \
      _Pragma("unroll")                                                        \
      for (int r = 0; r < 4; ++r) {                                            \
        float mx = fmaxf(fmaxf(ACC[rt][0][r], ACC[rt][1][r]),                  \
                         fmaxf(ACC[rt][2][r], ACC[rt][3][r]));                 \
        const float mnew = fmaxf(m_run[rt][r], mx);                            \
        float s = 0.f;                                                         \
        _Pragma("unroll")                                                      \
        for (int cs = 0; cs < 4; ++cs) s += fexp2(ACC[rt][cs][r] - mnew);      \
        l_run[rt][r] = l_run[rt][r] * fexp2(m_run[rt][r] - mnew) + s;          \
        m_run[rt][r] = mnew;                                                   \
      }                                                                        \
  }

  STAGE_TILE(0, col0)          // tile 0 -> buf0 (issue before afrag loads)

  // A-fragments: 16x16x32 bf16 A layout: row = lane&15, k = (lane>>4)*8 + j
  bf16x8 afrag[2][4];
#pragma unroll
  for (int rt = 0; rt < 2; ++rt)
#pragma unroll
    for (int kk = 0; kk < 4; ++kk) {
      const int r = rwave + rt * 16 + l15;
      afrag[rt][kk] = *reinterpret_cast<const bf16x8*>(zb + r * DD + kk * 32 + q * 8);
    }

  float m_run[2][4], l_run[2][4], stv[2][4];
#pragma unroll
  for (int rt = 0; rt < 2; ++rt)
#pragma unroll
    for (int r = 0; r < 4; ++r) { m_run[rt][r] = NEG_INF; l_run[rt][r] = 0.f; stv[rt][r] = NEG_INF; }

  __syncthreads();             // tile 0 staged

  f32x4 accA[2][4], accB[2][4];

  // ---- t = 0: fill the pipeline (MFMA only, no softmax yet) --------------
  STAGE_TILE(1, col0 + TILE_COLS)          // tile 1 -> buf1
  MFMA_TILE(accA, 0)                       // tile 0 from buf0
  __syncthreads();

  // ---- steady state: 2 tiles per iteration, named acc sets (rule #20) ----
  for (int tp = 1; tp + 1 < TILES_PER_SPLIT; tp += 2) {
    // t = tp (odd): reads buf1; stage tile tp+1 -> buf0
    STAGE_TILE(0, col0 + (tp + 1) * TILE_COLS)
    MFMA_TILE(accB, 1)
    SOFTMAX_TILE(accA, col0 + (tp - 1) * TILE_COLS)   // finish tile tp-1
    __syncthreads();

    // t = tp+1 (even): reads buf0; stage tile tp+2 -> buf1
    STAGE_TILE(1, col0 + (tp + 2) * TILE_COLS)
    MFMA_TILE(accA, 0)
    SOFTMAX_TILE(accB, col0 + tp * TILE_COLS)         // finish tile tp
    __syncthreads();
  }

  // ---- tail: t = 15 (odd, buf1), then drain both accumulators ------------
  MFMA_TILE(accB, 1)
  SOFTMAX_TILE(accA, col0 + (TILES_PER_SPLIT - 2) * TILE_COLS)  // tile 14
  SOFTMAX_TILE(accB, col0 + (TILES_PER_SPLIT - 1) * TILE_COLS)  // tile 15

  // ---- one-time cross-lane logsumexp merge over the 16-lane row slice ----
#pragma unroll
  for (int rt = 0; rt < 2; ++rt)
#pragma unroll
    for (int r = 0; r < 4; ++r) {
      float m = m_run[rt][r], l = l_run[rt][r];
#pragma unroll
      for (int off = 1; off < 16; off <<= 1) {
        const float mo = __shfl_xor(m, off, 64);
        const float lo = __shfl_xor(l, off, 64);
        const float mn = fmaxf(m, mo);
        l = l * fexp2(m - mn) + lo * fexp2(mo - mn);
        m = mn;
      }
      float sv = stv[rt][r];
#pragma unroll
      for (int off = 1; off < 16; off <<= 1) sv = fmaxf(sv, __shfl_xor(sv, off, 64));
      if (l15 == 0) {
        const int grow = rwave + rt * 16 + q * 4 + r;
        m_part[split * NTOT + grow] = m;
        l_part[split * NTOT + grow] = l;
        const int tcol = grow ^ BH;
        if (tcol >= col0 && tcol < col0 + COLS_PER_SPLIT) st_part[grow] = sv;  // one writer/row
      }
    }
#undef STAGE_TILE
#undef MFMA_TILE
#undef SOFTMAX_TILE
}

// ---- kernel 3: combine splits, mean, atomicAdd --------------------------
__global__ __launch_bounds__(256) void ntx_finish(
    const float* __restrict__ m_part, const float* __restrict__ l_part,
    const float* __restrict__ st_part, float* __restrict__ out) {
  const int row = blockIdx.x * 256 + threadIdx.x;   // 32 blocks
  float m = NEG_INF;
#pragma unroll
  for (int s = 0; s < COLSPLIT; ++s) m = fmaxf(m, m_part[s * NTOT + row]);
  float l = 0.f;
#pragma unroll
  for (int s = 0; s < COLSPLIT; ++s) l += l_part[s * NTOT + row] * fexp2(m_part[s * NTOT + row] - m);
  float loss = LN2F * (m + __log2f(l) - st_part[row]);  // back to natural-log domain

#pragma unroll
  for (int off = 32; off >= 1; off >>= 1) loss += __shfl_xor(loss, off, 64);
  __shared__ float wsum[4];
  if ((threadIdx.x & 63) == 0) wsum[threadIdx.x >> 6] = loss;
  __syncthreads();
  if (threadIdx.x == 0) {
    float s = wsum[0] + wsum[1] + wsum[2] + wsum[3];
    atomicAdd(out, s * (1.0f / NTOT));
  }
}

extern "C" void kernel_launch(void* const* d_in, const int* in_sizes, int n_in,
                              void* d_out, int out_size, void* d_ws, size_t ws_size,
                              hipStream_t stream) {
  const float* z1 = (const float*)d_in[0];
  const float* z2 = (const float*)d_in[1];
  float* out = (float*)d_out;

  // workspace: zb (2MB bf16) | m_part[8][8192] | l_part[8][8192] | st[8192]
  char* ws = (char*)d_ws;
  u16*   zb      = (u16*)ws;
  float* m_part  = (float*)(ws + (size_t)NTOT * DD * 2);
  float* l_part  = m_part + COLSPLIT * NTOT;
  float* st_part = l_part + COLSPLIT * NTOT;

  ntx_convert<<<dim3((NTOT * DD) / (256 * 4)), dim3(256), 0, stream>>>(z1, z2, zb, out);
  ntx_main<<<dim3(NTOT / ROWS_PER_BLOCK, COLSPLIT), dim3(256), 0, stream>>>(
      zb, m_part, l_part, st_part);
  ntx_finish<<<dim3(NTOT / 256), dim3(256), 0, stream>>>(m_part, l_part, st_part, out);
}